// Round 3
// baseline (82.198 us; speedup 1.0000x reference)
//
#include <hip/hip_runtime.h>
#include <math.h>

#define N 512
#define DIM 128
#define ROWS 64              // j-rows per staging pass
#define PASSES (N / ROWS)    // 8
#define TW 132               // tile row stride in floats (132 = 4 mod 32: full-bank b128 pattern)

// ws layout: sums[N] | cnts[N]   (no D matrix anymore)

// FUSED kernel: block per anchor i.  Recomputes its own D row instead of
// reading a precomputed gram matrix: x is 256 KB (L2/L3-resident), so the
// 512x redundant read is ~134 MB of L2 traffic (~4 us chip-wide) -- cheaper
// than a separate gram kernel + D round-trip + kernel boundary + ramp.
//   - 8 staging passes of 64 rows (33.8 KB LDS tile, static-safe, 3 blk/CU)
//   - T14 register prefetch: pass p+1's global loads issue before compute(p)
//   - anchor row broadcast from LDS (free), per-lane-row b128 B reads
//   - per-row inverse norms computed inline during staging (shfl over the
//     32-lane half-wave that stages each row)
//   - tail = ballot/popc compaction + esame precompute + log2 softplus
//     (verbatim from the working loss kernel)
__global__ void __launch_bounds__(256) fused_kernel(const float* __restrict__ x,
                                                    const int* __restrict__ labels,
                                                    float* __restrict__ sums,
                                                    float* __restrict__ cnts) {
    __shared__ float tile[ROWS * TW];     // 33792 B
    __shared__ float xrow[DIM];
    __shared__ float rnB[ROWS];
    __shared__ int   lab[N];
    __shared__ float sameD[N];
    __shared__ float diffD[N];
    __shared__ float esame[N];
    __shared__ int   cS[8], cD[8];
    __shared__ float red[4];
    __shared__ float rni_sh;

    int i = blockIdx.x, t = threadIdx.x;

    lab[t]       = labels[t];
    lab[t + 256] = labels[t + 256];

    // anchor row + its inverse norm (threads 0..31; 32 float4 = 128 floats)
    if (t < 32) {
        float4 v = ((const float4*)(x + i * DIM))[t];
        ((float4*)xrow)[t] = v;
        float s = v.x * v.x + v.y * v.y + v.z * v.z + v.w * v.w;
        s += __shfl_xor(s, 1, 64);
        s += __shfl_xor(s, 2, 64);
        s += __shfl_xor(s, 4, 64);
        s += __shfl_xor(s, 8, 64);
        s += __shfl_xor(s, 16, 64);
        if (t == 0) rni_sh = rsqrtf(s);
    }
    __syncthreads();
    float rni = rni_sh;
    int li = lab[i];

    // thread t owns j = t (active in pass t>>6) and j = t+256 (pass 4+(t>>6));
    // local row index is t&63 in both cases.
    int myw = t >> 6;
    int jl  = t & 63;
    float d0 = 0.0f, d1 = 0.0f;

    // prefetch pass 0
    float4 pre[8];
    {
        const float4* src = (const float4*)x;
        #pragma unroll
        for (int k = 0; k < 8; ++k) pre[k] = src[t + 256 * k];
    }

    for (int p = 0; p < PASSES; ++p) {
        // write prefetched tile + inline per-row norms.
        // e = t + 256k: row r = e>>5 (each 32-lane half-wave stages one row
        // per k), col group c4 = e&31.
        #pragma unroll
        for (int k = 0; k < 8; ++k) {
            int e = t + 256 * k;
            int r = e >> 5, c4 = e & 31;
            float4 v = pre[k];
            *((float4*)(tile + r * TW + 4 * c4)) = v;
            float s = v.x * v.x + v.y * v.y + v.z * v.z + v.w * v.w;
            s += __shfl_xor(s, 1, 64);
            s += __shfl_xor(s, 2, 64);
            s += __shfl_xor(s, 4, 64);
            s += __shfl_xor(s, 8, 64);
            s += __shfl_xor(s, 16, 64);
            if ((t & 31) == 0) rnB[r] = rsqrtf(s);
        }
        __syncthreads();

        // issue next pass's global loads BEFORE compute (latency hides here)
        if (p < PASSES - 1) {
            const float4* src = (const float4*)(x + (p + 1) * ROWS * DIM);
            #pragma unroll
            for (int k = 0; k < 8; ++k) pre[k] = src[t + 256 * k];
        }

        // compute: the wave owning these 64 rows does 1 dot/lane
        bool act0 = (p == myw);
        bool act1 = (p == 4 + myw);
        if (act0 || act1) {
            const float4* B = (const float4*)(tile + jl * TW);
            const float4* A = (const float4*)xrow;        // broadcast reads
            float acc = 0.0f;
            #pragma unroll 8
            for (int k4 = 0; k4 < DIM / 4; ++k4) {
                float4 a = A[k4], b = B[k4];
                acc += a.x * b.x + a.y * b.y + a.z * b.z + a.w * b.w;
            }
            float dv = 18.0f * fmaxf(0.0f, 1.0f - acc * rni * rnB[jl]);
            if (act0) d0 = dv;
            else      d1 = dv;
        }
        __syncthreads();
    }

    // ---- classification via ballot+popc prefix compaction ----
    int lane = t & 63, w = t >> 6;
    bool pS0 = (lab[t] == li) && (t != i);
    bool pD0 = (lab[t] != li);
    bool pS1 = (lab[t + 256] == li) && ((t + 256) != i);
    bool pD1 = (lab[t + 256] != li);
    unsigned long long bS0 = __ballot(pS0);
    unsigned long long bD0 = __ballot(pD0);
    unsigned long long bS1 = __ballot(pS1);
    unsigned long long bD1 = __ballot(pD1);
    if (lane == 0) {
        cS[w]     = __popcll(bS0); cD[w]     = __popcll(bD0);
        cS[w + 4] = __popcll(bS1); cD[w + 4] = __popcll(bD1);
    }
    __syncthreads();
    int baseS0 = 0, baseD0 = 0, baseS1 = 0, baseD1 = 0, ns = 0, nd = 0;
    #pragma unroll
    for (int s = 0; s < 8; ++s) {
        int cs = cS[s], cd = cD[s];
        if (s < w)     { baseS0 += cs; baseD0 += cd; }
        if (s < w + 4) { baseS1 += cs; baseD1 += cd; }
        ns += cs; nd += cd;
    }
    unsigned long long lt = (1ull << lane) - 1ull;
    if (pS0) sameD[baseS0 + __popcll(bS0 & lt)] = d0;
    if (pD0) diffD[baseD0 + __popcll(bD0 & lt)] = d0;
    if (pS1) sameD[baseS1 + __popcll(bS1 & lt)] = d1;
    if (pD1) diffD[baseD1 + __popcll(bD1 & lt)] = d1;
    __syncthreads();

    // exp(sameD) once
    if (t < ns)       esame[t]       = __expf(sameD[t]);
    if (t + 256 < ns) esame[t + 256] = __expf(sameD[t + 256]);
    __syncthreads();

    // softplus(s - k) = ln2 * log2(1 + e^s * e^-k); s in [0,36]: no overflow
    float ek0 = (t < nd)       ? __expf(-diffD[t])       : 0.0f;
    float ek1 = (t + 256 < nd) ? __expf(-diffD[t + 256]) : 0.0f;
    float lsum = 0.0f;
    for (int js = 0; js < ns; ++js) {
        float es = esame[js];              // LDS broadcast read
        lsum += __log2f(fmaf(es, ek0, 1.0f)) + __log2f(fmaf(es, ek1, 1.0f));
    }
    lsum *= 0.6931471805599453f;

    #pragma unroll
    for (int off = 32; off > 0; off >>= 1) lsum += __shfl_xor(lsum, off, 64);
    if ((t & 63) == 0) red[t >> 6] = lsum;
    __syncthreads();
    if (t == 0) {
        sums[i] = red[0] + red[1] + red[2] + red[3];
        cnts[i] = (float)(ns * nd);
    }
}

// Finalize: single 64-lane wave, no LDS, no barriers. 512 partials each.
__global__ void __launch_bounds__(64) finalize_kernel(const float* __restrict__ sums,
                                                      const float* __restrict__ cnts,
                                                      float* __restrict__ out) {
    int t = threadIdx.x;
    const float4* S = (const float4*)sums;   // 128 float4
    const float4* C = (const float4*)cnts;
    float4 s0 = S[t], s1 = S[t + 64];
    float4 c0 = C[t], c1 = C[t + 64];
    float s = s0.x + s0.y + s0.z + s0.w + s1.x + s1.y + s1.z + s1.w;
    float c = c0.x + c0.y + c0.z + c0.w + c1.x + c1.y + c1.z + c1.w;
    #pragma unroll
    for (int off = 32; off > 0; off >>= 1) {
        s += __shfl_xor(s, off, 64);
        c += __shfl_xor(c, off, 64);
    }
    if (t == 0) out[0] = s / c;
}

extern "C" void kernel_launch(void* const* d_in, const int* in_sizes, int n_in,
                              void* d_out, int out_size, void* d_ws, size_t ws_size,
                              hipStream_t stream) {
    const float* x      = (const float*)d_in[0];
    const int*   labels = (const int*)d_in[1];
    float*       out    = (float*)d_out;

    float* sums = (float*)d_ws;       // 512 floats
    float* cnts = sums + N;           // 512 floats

    fused_kernel<<<N, 256, 0, stream>>>(x, labels, sums, cnts);
    finalize_kernel<<<1, 64, 0, stream>>>(sums, cnts, out);
}

// Round 5
// 63.769 us; speedup vs baseline: 1.2890x; 1.2890x over previous
//
#include <hip/hip_runtime.h>
#include <math.h>

#define N 512
#define DIM 128
#define TT 32            // D-tile edge (i and j) in gram kernel
#define PADS 132         // padded LDS row stride (floats), float4-aligned
#define NTRI (16 * 17 / 2)   // 136 lower-triangle tile blocks

// ws layout: D[N*N] | sums[N] | cnts[N]

// Kernel A: D[i][j] = 18*max(0, 1 - dot(x_i,x_j)*rn_i*rn_j), SYMMETRIC:
// triangular grid of 136 blocks; off-diagonal tiles are computed once and
// written twice (direct + LDS-transposed mirror, reusing the xi staging buf).
// 2x2 micro-tile with CONFLICT-AWARE mapping: thread (ty,tx) owns rows
// {ty, ty+16} x cols {tx, tx+16}.  B-row LDS word base = 132*tx -> start
// bank 4*tx mod 32 = 8 distinct bank-quads (2-way aliasing = free, m136).
// A-row reads are same-address broadcasts across the 16 tx lanes (free).
// Diagonal blocks (bi==bj) skip xj staging and alias B at xi.
__global__ void __launch_bounds__(256) gram_kernel(const float* __restrict__ x,
                                                   float* __restrict__ D) {
    __shared__ float xi[TT * PADS];
    __shared__ float xj[TT * PADS];
    __shared__ float rnA[TT];
    __shared__ float rnB[TT];

    int t = threadIdx.x;

    // linear block index -> (bi, bj), bj <= bi (lower triangle)
    int b = blockIdx.x;
    int bi = (int)((sqrtf(8.0f * (float)b + 1.0f) - 1.0f) * 0.5f);
    while ((bi + 1) * (bi + 2) / 2 <= b) ++bi;   // float fixup
    while (bi * (bi + 1) / 2 > b) --bi;
    int bj = b - bi * (bi + 1) / 2;
    bool offdiag = (bi != bj);

    // stage tiles, coalesced float4 (4 per thread per tile); diag: xi only
    const float4* srcA = (const float4*)(x + bi * TT * DIM);
    const float4* srcB = (const float4*)(x + bj * TT * DIM);
    #pragma unroll
    for (int k = 0; k < (TT * DIM / 4) / 256; ++k) {
        int e = t + k * 256;
        int r = e >> 5, c4 = e & 31;       // 32 float4 per row
        *((float4*)(xi + r * PADS + 4 * c4)) = srcA[e];
        if (offdiag)
            *((float4*)(xj + r * PADS + 4 * c4)) = srcB[e];
    }
    __syncthreads();

    const float* xjp = offdiag ? xj : xi;   // B tile (aliases xi on diagonal)

    // inverse norms: 4 threads/row x 64 rows (32 from each tile), shfl reduce
    // (diag blocks: rows 32..63 read the aliased xi -> rnB == rnA, correct)
    {
        int quart = t & 3, r = t >> 2;     // r: 0..63
        const float* base = (r < TT) ? (xi + r * PADS) : (xjp + (r - TT) * PADS);
        const float4* a = (const float4*)(base + quart * 32);
        float s0 = 0.0f, s1 = 0.0f;
        #pragma unroll
        for (int q = 0; q < 8; q += 2) {
            float4 a0 = a[q], a1 = a[q + 1];
            s0 += a0.x * a0.x + a0.y * a0.y + a0.z * a0.z + a0.w * a0.w;
            s1 += a1.x * a1.x + a1.y * a1.y + a1.z * a1.z + a1.w * a1.w;
        }
        float ss = s0 + s1;
        ss += __shfl_xor(ss, 1, 64);
        ss += __shfl_xor(ss, 2, 64);
        if (quart == 0) {
            if (r < TT) rnA[r] = rsqrtf(ss);
            else        rnB[r - TT] = rsqrtf(ss);
        }
    }
    __syncthreads();

    int tx = t & 15, ty = t >> 4;
    int i0 = ty, i1 = ty + 16, j0 = tx, j1 = tx + 16;
    float acc00 = 0.0f, acc01 = 0.0f, acc10 = 0.0f, acc11 = 0.0f;
    const float4* A0 = (const float4*)(xi + i0 * PADS);
    const float4* A1 = (const float4*)(xi + i1 * PADS);
    const float4* B0 = (const float4*)(xjp + j0 * PADS);
    const float4* B1 = (const float4*)(xjp + j1 * PADS);
    #pragma unroll 8
    for (int k4 = 0; k4 < DIM / 4; ++k4) {
        float4 a0 = A0[k4], a1 = A1[k4], b0 = B0[k4], b1 = B1[k4];
        acc00 += a0.x * b0.x + a0.y * b0.y + a0.z * b0.z + a0.w * b0.w;
        acc01 += a0.x * b1.x + a0.y * b1.y + a0.z * b1.z + a0.w * b1.w;
        acc10 += a1.x * b0.x + a1.y * b0.y + a1.z * b0.z + a1.w * b0.w;
        acc11 += a1.x * b1.x + a1.y * b1.y + a1.z * b1.z + a1.w * b1.w;
    }
    float ri0 = rnA[i0], ri1 = rnA[i1], rj0 = rnB[j0], rj1 = rnB[j1];
    // T[a][b] = D value at global (bi*32+a, bj*32+b)
    float t00 = 18.0f * fmaxf(0.0f, 1.0f - acc00 * ri0 * rj0);
    float t01 = 18.0f * fmaxf(0.0f, 1.0f - acc01 * ri0 * rj1);
    float t10 = 18.0f * fmaxf(0.0f, 1.0f - acc10 * ri1 * rj0);
    float t11 = 18.0f * fmaxf(0.0f, 1.0f - acc11 * ri1 * rj1);

    // direct write: 4 dword stores, each quarter-wave covers 64B contiguous
    {
        int gi0 = bi * TT + i0, gi1 = bi * TT + i1;
        int gj0 = bj * TT + j0, gj1 = bj * TT + j1;
        D[gi0 * N + gj0] = t00;
        D[gi0 * N + gj1] = t01;
        D[gi1 * N + gj0] = t10;
        D[gi1 * N + gj1] = t11;
    }

    if (offdiag) {
        // mirror write via LDS transpose; xi is dead now, reuse as Tt[32][33]
        __syncthreads();                    // everyone done reading xi
        float* Tt = xi;                     // Tt[j][i] = T[i][j], stride 33
        Tt[j0 * 33 + i0] = t00;
        Tt[j1 * 33 + i0] = t01;
        Tt[j0 * 33 + i1] = t10;
        Tt[j1 * 33 + i1] = t11;
        __syncthreads();
        // mirror region: D[bj*32 + a][bi*32 + c] = T[c][a] = Tt[a][c]
        float m00 = Tt[i0 * 33 + j0], m01 = Tt[i0 * 33 + j1];
        float m10 = Tt[i1 * 33 + j0], m11 = Tt[i1 * 33 + j1];
        int ga0 = bj * TT + i0, ga1 = bj * TT + i1;
        int gb0 = bi * TT + j0, gb1 = bi * TT + j1;
        D[ga0 * N + gb0] = m00;
        D[ga0 * N + gb1] = m01;
        D[ga1 * N + gb0] = m10;
        D[ga1 * N + gb1] = m11;
    }
}

// Kernel B: block per anchor i. Read D row i (2 KB, coalesced), compact
// same/diff lists via ballot+popc prefix (no LDS atomics), precompute
// exp(sameD) once into LDS, thread-per-k softplus (2 k/thread), per-block
// partial.  NO grid-wide rendezvous: cg.sync (+50us), same-address device
// atomics (~18us) and fence-heavy last-block-done (+45us) all lose to a
// ~1us kernel boundary on this chip (prev session R1/R5/R8).
__global__ void __launch_bounds__(256) loss_kernel(const float* __restrict__ Dm,
                                                   const int* __restrict__ labels,
                                                   float* __restrict__ sums,
                                                   float* __restrict__ cnts) {
    __shared__ int   lab[N];
    __shared__ float sameD[N];
    __shared__ float diffD[N];
    __shared__ float esame[N];
    __shared__ int   cS[8], cD[8];
    __shared__ float red[4];

    int i = blockIdx.x, t = threadIdx.x;
    lab[t]       = labels[t];
    lab[t + 256] = labels[t + 256];
    float d0 = Dm[i * N + t];
    float d1 = Dm[i * N + t + 256];
    __syncthreads();

    int li = lab[i];
    int lane = t & 63, w = t >> 6;          // 4 waves; 8 compaction segments
    bool pS0 = (lab[t] == li) && (t != i);
    bool pD0 = (lab[t] != li);
    bool pS1 = (lab[t + 256] == li) && ((t + 256) != i);
    bool pD1 = (lab[t + 256] != li);
    unsigned long long bS0 = __ballot(pS0);
    unsigned long long bD0 = __ballot(pD0);
    unsigned long long bS1 = __ballot(pS1);
    unsigned long long bD1 = __ballot(pD1);
    if (lane == 0) {
        cS[w]     = __popcll(bS0); cD[w]     = __popcll(bD0);
        cS[w + 4] = __popcll(bS1); cD[w + 4] = __popcll(bD1);
    }
    __syncthreads();
    int baseS0 = 0, baseD0 = 0, baseS1 = 0, baseD1 = 0, ns = 0, nd = 0;
    #pragma unroll
    for (int s = 0; s < 8; ++s) {
        int cs = cS[s], cd = cD[s];
        if (s < w)     { baseS0 += cs; baseD0 += cd; }
        if (s < w + 4) { baseS1 += cs; baseD1 += cd; }
        ns += cs; nd += cd;
    }
    unsigned long long lt = (1ull << lane) - 1ull;
    if (pS0) sameD[baseS0 + __popcll(bS0 & lt)] = d0;
    if (pD0) diffD[baseD0 + __popcll(bD0 & lt)] = d0;
    if (pS1) sameD[baseS1 + __popcll(bS1 & lt)] = d1;
    if (pD1) diffD[baseD1 + __popcll(bD1 & lt)] = d1;
    __syncthreads();

    // exp(sameD) once; all 256 threads then only pay logs in the js loop
    if (t < ns)       esame[t]       = __expf(sameD[t]);
    if (t + 256 < ns) esame[t + 256] = __expf(sameD[t + 256]);
    __syncthreads();

    // softplus(s - k) = ln2 * log2(1 + e^s * e^-k); s in [0,36]: no overflow
    float ek0 = (t < nd)       ? __expf(-diffD[t])       : 0.0f;  // 0 -> log(1)=0
    float ek1 = (t + 256 < nd) ? __expf(-diffD[t + 256]) : 0.0f;
    float lsum = 0.0f;
    for (int js = 0; js < ns; ++js) {
        float es = esame[js];              // LDS broadcast read
        lsum += __log2f(fmaf(es, ek0, 1.0f)) + __log2f(fmaf(es, ek1, 1.0f));
    }
    lsum *= 0.6931471805599453f;

    #pragma unroll
    for (int off = 32; off > 0; off >>= 1) lsum += __shfl_xor(lsum, off, 64);
    if ((t & 63) == 0) red[t >> 6] = lsum;
    __syncthreads();
    if (t == 0) {
        sums[i] = red[0] + red[1] + red[2] + red[3];
        cnts[i] = (float)(ns * nd);
    }
}

// Kernel C: single 64-lane wave, registers + shfl only (no LDS, no barriers
// -- a 1-block kernel's latency is pure serial depth, so strip everything).
__global__ void __launch_bounds__(64) finalize_kernel(const float* __restrict__ sums,
                                                      const float* __restrict__ cnts,
                                                      float* __restrict__ out) {
    int t = threadIdx.x;
    const float4* S = (const float4*)sums;   // 128 float4
    const float4* C = (const float4*)cnts;
    float4 s0 = S[t], s1 = S[t + 64];
    float4 c0 = C[t], c1 = C[t + 64];
    float s = s0.x + s0.y + s0.z + s0.w + s1.x + s1.y + s1.z + s1.w;
    float c = c0.x + c0.y + c0.z + c0.w + c1.x + c1.y + c1.z + c1.w;
    #pragma unroll
    for (int off = 32; off > 0; off >>= 1) {
        s += __shfl_xor(s, off, 64);
        c += __shfl_xor(c, off, 64);
    }
    if (t == 0) out[0] = s / c;
}

extern "C" void kernel_launch(void* const* d_in, const int* in_sizes, int n_in,
                              void* d_out, int out_size, void* d_ws, size_t ws_size,
                              hipStream_t stream) {
    const float* x      = (const float*)d_in[0];
    const int*   labels = (const int*)d_in[1];
    float*       out    = (float*)d_out;

    float* Dm   = (float*)d_ws;       // 512*512 floats = 1 MB
    float* sums = Dm + N * N;         // 512 floats
    float* cnts = sums + N;           // 512 floats

    gram_kernel<<<NTRI, 256, 0, stream>>>(x, Dm);
    loss_kernel<<<N, 256, 0, stream>>>(Dm, labels, sums, cnts);
    finalize_kernel<<<1, 64, 0, stream>>>(sums, cnts, out);
}